// Round 1
// baseline (980.337 us; speedup 1.0000x reference)
//
#include <hip/hip_runtime.h>

#define NUSERS 100000
#define NITEMS 50000
#define NTOT   150000
#define NEDGE  1000000

// ---- init: emb = concat(user, item); out = emb (embeds_lst[0]) ----
__global__ void k_init(const float* __restrict__ ue, const float* __restrict__ ie,
                       float* __restrict__ emb, float* __restrict__ out) {
  int i = blockIdx.x * 256 + threadIdx.x;  // float4 index
  if (i >= NTOT * 16) return;
  float4 v = (i < NUSERS * 16) ? ((const float4*)ue)[i]
                               : ((const float4*)ie)[i - NUSERS * 16];
  ((float4*)emb)[i] = v;
  ((float4*)out)[i] = v;
}

// ---- CSR build: histogram -> scan -> fill ----
__global__ void k_hist(const int* __restrict__ rows, int* __restrict__ cnt) {
  int e = blockIdx.x * 256 + threadIdx.x;
  if (e < NEDGE) atomicAdd(&cnt[rows[e]], 1);
}

__global__ void k_scan1(const int* __restrict__ cnt, int* __restrict__ partial,
                        int* __restrict__ blocksums) {
  __shared__ int s[256];
  int t = threadIdx.x, b = blockIdx.x;
  int base = b * 2048 + t * 8;
  int pre[8]; int sum = 0;
  #pragma unroll
  for (int j = 0; j < 8; ++j) {
    int idx = base + j;
    int x = (idx < NTOT) ? cnt[idx] : 0;
    pre[j] = sum; sum += x;
  }
  s[t] = sum; __syncthreads();
  for (int off = 1; off < 256; off <<= 1) {
    int x = (t >= off) ? s[t - off] : 0;
    __syncthreads(); s[t] += x; __syncthreads();
  }
  int excl = s[t] - sum;
  #pragma unroll
  for (int j = 0; j < 8; ++j) {
    int idx = base + j;
    if (idx < NTOT) partial[idx] = excl + pre[j];
  }
  if (t == 255) blocksums[b] = s[255];
}

__global__ void k_scan2(const int* __restrict__ blocksums, int* __restrict__ blockoffs, int nblk) {
  __shared__ int s[128];
  int t = threadIdx.x;
  int x = (t < nblk) ? blocksums[t] : 0;
  s[t] = x; __syncthreads();
  for (int off = 1; off < 128; off <<= 1) {
    int y = (t >= off) ? s[t - off] : 0;
    __syncthreads(); s[t] += y; __syncthreads();
  }
  if (t < nblk) blockoffs[t] = s[t] - x;
}

__global__ void k_scan3(int* __restrict__ row_ptr, const int* __restrict__ blockoffs,
                        int* __restrict__ cursor) {
  int i = blockIdx.x * 256 + threadIdx.x;
  if (i < NTOT) {
    int v = row_ptr[i] + blockoffs[i >> 11];
    row_ptr[i] = v; cursor[i] = v;
  }
  if (i == 0) row_ptr[NTOT] = NEDGE;
}

__global__ void k_fill(const int* __restrict__ rows, const int* __restrict__ cols,
                       const float* __restrict__ vals, int* __restrict__ cursor,
                       int* __restrict__ ecols, float* __restrict__ evals) {
  int e = blockIdx.x * 256 + threadIdx.x;
  if (e >= NEDGE) return;
  int r = rows[e];
  int pos = atomicAdd(&cursor[r], 1);
  ecols[pos] = cols[e];
  evals[pos] = vals[e];
}

// ---- QKV projection: one wave handles 8 nodes; lane = output dim ----
__global__ void __launch_bounds__(256) k_qkv(const float* __restrict__ emb,
    const float* __restrict__ Wq, const float* __restrict__ Wk, const float* __restrict__ Wv,
    float* __restrict__ Q, float* __restrict__ K, float* __restrict__ V) {
  __shared__ float wq[4096], wk[4096], wv[4096];
  int t = threadIdx.x;
  for (int i = t; i < 4096; i += 256) { wq[i] = Wq[i]; wk[i] = Wk[i]; wv[i] = Wv[i]; }
  __syncthreads();
  int wave = blockIdx.x * 4 + (t >> 6);
  if (wave >= NTOT / 8) return;
  int lane = t & 63;
  int n0 = wave * 8;
  float e[8];
  float qa[8] = {0,0,0,0,0,0,0,0};
  float ka[8] = {0,0,0,0,0,0,0,0};
  float va[8] = {0,0,0,0,0,0,0,0};
  #pragma unroll
  for (int i = 0; i < 8; ++i) e[i] = emb[(n0 + i) * 64 + lane];
  for (int k = 0; k < 64; ++k) {
    float a = wq[k * 64 + lane], bb = wk[k * 64 + lane], c = wv[k * 64 + lane];
    #pragma unroll
    for (int i = 0; i < 8; ++i) {
      float x = __shfl(e[i], k, 64);
      qa[i] = fmaf(x, a, qa[i]);
      ka[i] = fmaf(x, bb, ka[i]);
      va[i] = fmaf(x, c, va[i]);
    }
  }
  #pragma unroll
  for (int i = 0; i < 8; ++i) {
    Q[(n0 + i) * 64 + lane] = qa[i];
    K[(n0 + i) * 64 + lane] = ka[i];
    V[(n0 + i) * 64 + lane] = va[i];
  }
}

// ---- GT layer: one wave per destination node, single fused pass ----
// out[n] = (sum_e exp(clip(q_n . k_{c_e} per head)) * v_{c_e}) / (denom + 1e-8)
__global__ void __launch_bounds__(256) k_gt(const float* __restrict__ Q, const float* __restrict__ K,
    const float* __restrict__ V, const int* __restrict__ row_ptr, const int* __restrict__ ecols,
    float* __restrict__ emb_out, float* __restrict__ acc_out) {
  int t = threadIdx.x;
  int n = blockIdx.x * 4 + (t >> 6);
  if (n >= NTOT) return;
  int lane = t & 63;
  float q = Q[n * 64 + lane];
  int s = row_ptr[n], e_end = row_ptr[n + 1];
  float denom = 0.f, acc = 0.f;
  for (int p = s; p < e_end; ++p) {
    int c = ecols[p];
    float kv = K[c * 64 + lane];
    float vv = V[c * 64 + lane];
    float x = q * kv;
    x += __shfl_xor(x, 1);
    x += __shfl_xor(x, 2);
    x += __shfl_xor(x, 4);
    x += __shfl_xor(x, 8);   // per-16-lane head-group sum
    x = fminf(fmaxf(x, -10.f), 10.f);
    float ex = __expf(x);
    denom += ex;
    acc = fmaf(ex, vv, acc);
  }
  float r = acc / (denom + 1e-8f);
  emb_out[n * 64 + lane] = r;
  acc_out[n * 64 + lane] += r;
}

// ---- GCN layer (spmm): one wave per destination node ----
__global__ void __launch_bounds__(256) k_gcn(const float* __restrict__ emb,
    const int* __restrict__ row_ptr, const int* __restrict__ ecols, const float* __restrict__ evals,
    float* __restrict__ emb_out, float* __restrict__ acc_out) {
  int t = threadIdx.x;
  int n = blockIdx.x * 4 + (t >> 6);
  if (n >= NTOT) return;
  int lane = t & 63;
  int s = row_ptr[n], e_end = row_ptr[n + 1];
  float acc = 0.f;
  for (int p = s; p < e_end; ++p) {
    int c = ecols[p];
    float v = evals[p];
    acc = fmaf(v, emb[c * 64 + lane], acc);
  }
  emb_out[n * 64 + lane] = acc;
  acc_out[n * 64 + lane] += acc;
}

extern "C" void kernel_launch(void* const* d_in, const int* in_sizes, int n_in,
                              void* d_out, int out_size, void* d_ws, size_t ws_size,
                              hipStream_t stream) {
  const int*   rows = (const int*)d_in[0];
  const int*   cols = (const int*)d_in[1];
  const float* vals = (const float*)d_in[2];
  const float* ue   = (const float*)d_in[3];
  const float* ie   = (const float*)d_in[4];
  const float* Wq   = (const float*)d_in[5];
  const float* Wk   = (const float*)d_in[6];
  const float* Wv   = (const float*)d_in[7];
  float* out = (float*)d_out;

  char* p = (char*)d_ws;
  auto alloc = [&](size_t b) { char* r = p; p += (b + 255) & ~(size_t)255; return (void*)r; };
  int*   cnt     = (int*)alloc((size_t)NTOT * 4);
  int*   row_ptr = (int*)alloc((size_t)(NTOT + 1) * 4);
  int*   cursor  = (int*)alloc((size_t)NTOT * 4);
  int*   bsums   = (int*)alloc(128 * 4);
  int*   boffs   = (int*)alloc(128 * 4);
  int*   ecols   = (int*)alloc((size_t)NEDGE * 4);
  float* evals   = (float*)alloc((size_t)NEDGE * 4);
  float* Q    = (float*)alloc((size_t)NTOT * 64 * 4);
  float* K    = (float*)alloc((size_t)NTOT * 64 * 4);
  float* V    = (float*)alloc((size_t)NTOT * 64 * 4);
  float* embA = (float*)alloc((size_t)NTOT * 64 * 4);
  float* embB = (float*)alloc((size_t)NTOT * 64 * 4);

  hipMemsetAsync(cnt, 0, (size_t)NTOT * 4, stream);
  k_hist<<<(NEDGE + 255) / 256, 256, 0, stream>>>(rows, cnt);
  int nblk = (NTOT + 2047) / 2048;  // 74
  k_scan1<<<nblk, 256, 0, stream>>>(cnt, row_ptr, bsums);
  k_scan2<<<1, 128, 0, stream>>>(bsums, boffs, nblk);
  k_scan3<<<(NTOT + 255) / 256, 256, 0, stream>>>(row_ptr, boffs, cursor);
  k_fill<<<(NEDGE + 255) / 256, 256, 0, stream>>>(rows, cols, vals, cursor, ecols, evals);
  k_init<<<(NTOT * 16 + 255) / 256, 256, 0, stream>>>(ue, ie, embA, out);

  float* cur = embA;
  float* nxt = embB;
  for (int l = 0; l < 2; ++l) {
    k_qkv<<<(NTOT / 8 + 3) / 4, 256, 0, stream>>>(cur, Wq + l * 4096, Wk + l * 4096, Wv + l * 4096,
                                                  Q, K, V);
    k_gt<<<(NTOT + 3) / 4, 256, 0, stream>>>(Q, K, V, row_ptr, ecols, nxt, out);
    float* tmp = cur; cur = nxt; nxt = tmp;
  }
  for (int l = 0; l < 2; ++l) {
    k_gcn<<<(NTOT + 3) / 4, 256, 0, stream>>>(cur, row_ptr, ecols, evals, nxt, out);
    float* tmp = cur; cur = nxt; nxt = tmp;
  }
}

// Round 2
// 769.433 us; speedup vs baseline: 1.2741x; 1.2741x over previous
//
#include <hip/hip_runtime.h>

#define NUSERS 100000
#define NITEMS 50000
#define NTOT   150000
#define NEDGE  1000000

// ---- init: emb = concat(user, item); out = emb (embeds_lst[0]) ----
__global__ void k_init(const float* __restrict__ ue, const float* __restrict__ ie,
                       float* __restrict__ emb, float* __restrict__ out) {
  int i = blockIdx.x * 256 + threadIdx.x;  // float4 index
  if (i >= NTOT * 16) return;
  float4 v = (i < NUSERS * 16) ? ((const float4*)ue)[i]
                               : ((const float4*)ie)[i - NUSERS * 16];
  ((float4*)emb)[i] = v;
  ((float4*)out)[i] = v;
}

// ---- CSR build: histogram -> scan -> fill ----
__global__ void k_hist(const int* __restrict__ rows, int* __restrict__ cnt) {
  int e = blockIdx.x * 256 + threadIdx.x;
  if (e < NEDGE) atomicAdd(&cnt[rows[e]], 1);
}

__global__ void k_scan1(const int* __restrict__ cnt, int* __restrict__ partial,
                        int* __restrict__ blocksums) {
  __shared__ int s[256];
  int t = threadIdx.x, b = blockIdx.x;
  int base = b * 2048 + t * 8;
  int pre[8]; int sum = 0;
  #pragma unroll
  for (int j = 0; j < 8; ++j) {
    int idx = base + j;
    int x = (idx < NTOT) ? cnt[idx] : 0;
    pre[j] = sum; sum += x;
  }
  s[t] = sum; __syncthreads();
  for (int off = 1; off < 256; off <<= 1) {
    int x = (t >= off) ? s[t - off] : 0;
    __syncthreads(); s[t] += x; __syncthreads();
  }
  int excl = s[t] - sum;
  #pragma unroll
  for (int j = 0; j < 8; ++j) {
    int idx = base + j;
    if (idx < NTOT) partial[idx] = excl + pre[j];
  }
  if (t == 255) blocksums[b] = s[255];
}

__global__ void k_scan2(const int* __restrict__ blocksums, int* __restrict__ blockoffs, int nblk) {
  __shared__ int s[128];
  int t = threadIdx.x;
  int x = (t < nblk) ? blocksums[t] : 0;
  s[t] = x; __syncthreads();
  for (int off = 1; off < 128; off <<= 1) {
    int y = (t >= off) ? s[t - off] : 0;
    __syncthreads(); s[t] += y; __syncthreads();
  }
  if (t < nblk) blockoffs[t] = s[t] - x;
}

__global__ void k_scan3(int* __restrict__ row_ptr, const int* __restrict__ blockoffs,
                        int* __restrict__ cursor) {
  int i = blockIdx.x * 256 + threadIdx.x;
  if (i < NTOT) {
    int v = row_ptr[i] + blockoffs[i >> 11];
    row_ptr[i] = v; cursor[i] = v;
  }
  if (i == 0) row_ptr[NTOT] = NEDGE;
}

__global__ void k_fill(const int* __restrict__ rows, const int* __restrict__ cols,
                       const float* __restrict__ vals, int* __restrict__ cursor,
                       int* __restrict__ ecols, float* __restrict__ evals) {
  int e = blockIdx.x * 256 + threadIdx.x;
  if (e >= NEDGE) return;
  int r = rows[e];
  int pos = atomicAdd(&cursor[r], 1);
  ecols[pos] = cols[e];
  evals[pos] = vals[e];
}

// ---- QKV projection: one wave handles 8 nodes; lane = output dim ----
// Writes Q[n][64] and interleaved KV[n][128] (K in [0,64), V in [64,128))
__global__ void __launch_bounds__(256) k_qkv(const float* __restrict__ emb,
    const float* __restrict__ Wq, const float* __restrict__ Wk, const float* __restrict__ Wv,
    float* __restrict__ Q, float* __restrict__ KV) {
  __shared__ float wq[4096], wk[4096], wv[4096];
  int t = threadIdx.x;
  for (int i = t; i < 4096; i += 256) { wq[i] = Wq[i]; wk[i] = Wk[i]; wv[i] = Wv[i]; }
  __syncthreads();
  int wave = blockIdx.x * 4 + (t >> 6);
  if (wave >= NTOT / 8) return;
  int lane = t & 63;
  int n0 = wave * 8;
  float e[8];
  float qa[8] = {0,0,0,0,0,0,0,0};
  float ka[8] = {0,0,0,0,0,0,0,0};
  float va[8] = {0,0,0,0,0,0,0,0};
  #pragma unroll
  for (int i = 0; i < 8; ++i) e[i] = emb[(n0 + i) * 64 + lane];
  for (int k = 0; k < 64; ++k) {
    float a = wq[k * 64 + lane], bb = wk[k * 64 + lane], c = wv[k * 64 + lane];
    #pragma unroll
    for (int i = 0; i < 8; ++i) {
      float x = __shfl(e[i], k, 64);
      qa[i] = fmaf(x, a, qa[i]);
      ka[i] = fmaf(x, bb, ka[i]);
      va[i] = fmaf(x, c, va[i]);
    }
  }
  #pragma unroll
  for (int i = 0; i < 8; ++i) {
    Q[(n0 + i) * 64 + lane] = qa[i];
    KV[(n0 + i) * 128 + lane] = ka[i];
    KV[(n0 + i) * 128 + 64 + lane] = va[i];
  }
}

__device__ __forceinline__ float head_sum16(float x) {
  x += __shfl_xor(x, 1);
  x += __shfl_xor(x, 2);
  x += __shfl_xor(x, 4);
  x += __shfl_xor(x, 8);
  return x;
}

// ---- GT layer: one wave per destination node, 4x unrolled edge loop ----
__global__ void __launch_bounds__(256) k_gt(const float* __restrict__ Q,
    const float* __restrict__ KV, const int* __restrict__ row_ptr,
    const int* __restrict__ ecols, float* __restrict__ emb_out, float* __restrict__ acc_out) {
  int t = threadIdx.x;
  int n = blockIdx.x * 4 + (t >> 6);
  if (n >= NTOT) return;
  int lane = t & 63;
  float q = Q[n * 64 + lane];
  int s     = __builtin_amdgcn_readfirstlane(row_ptr[n]);
  int e_end = __builtin_amdgcn_readfirstlane(row_ptr[n + 1]);
  float den0 = 0.f, den1 = 0.f, acc0 = 0.f, acc1 = 0.f;
  int p = s;
  for (; p + 4 <= e_end; p += 4) {
    int c0 = ecols[p], c1 = ecols[p + 1], c2 = ecols[p + 2], c3 = ecols[p + 3];
    const float* b0 = KV + c0 * 128;
    const float* b1 = KV + c1 * 128;
    const float* b2 = KV + c2 * 128;
    const float* b3 = KV + c3 * 128;
    float k0 = b0[lane], k1 = b1[lane], k2 = b2[lane], k3 = b3[lane];
    float v0 = b0[64 + lane], v1 = b1[64 + lane], v2 = b2[64 + lane], v3 = b3[64 + lane];
    float x0 = head_sum16(q * k0);
    float x1 = head_sum16(q * k1);
    float x2 = head_sum16(q * k2);
    float x3 = head_sum16(q * k3);
    float e0 = __expf(fminf(fmaxf(x0, -10.f), 10.f));
    float e1 = __expf(fminf(fmaxf(x1, -10.f), 10.f));
    float e2 = __expf(fminf(fmaxf(x2, -10.f), 10.f));
    float e3 = __expf(fminf(fmaxf(x3, -10.f), 10.f));
    den0 += e0; den1 += e1; den0 += e2; den1 += e3;
    acc0 = fmaf(e0, v0, acc0); acc1 = fmaf(e1, v1, acc1);
    acc0 = fmaf(e2, v2, acc0); acc1 = fmaf(e3, v3, acc1);
  }
  for (; p < e_end; ++p) {
    int c = ecols[p];
    const float* b = KV + c * 128;
    float kv = b[lane], vv = b[64 + lane];
    float x = head_sum16(q * kv);
    float ex = __expf(fminf(fmaxf(x, -10.f), 10.f));
    den0 += ex;
    acc0 = fmaf(ex, vv, acc0);
  }
  float r = (acc0 + acc1) / ((den0 + den1) + 1e-8f);
  emb_out[n * 64 + lane] = r;
  acc_out[n * 64 + lane] += r;
}

// ---- GCN layer (spmm): one wave per destination node, 4x unrolled ----
__global__ void __launch_bounds__(256) k_gcn(const float* __restrict__ emb,
    const int* __restrict__ row_ptr, const int* __restrict__ ecols, const float* __restrict__ evals,
    float* __restrict__ emb_out, float* __restrict__ acc_out) {
  int t = threadIdx.x;
  int n = blockIdx.x * 4 + (t >> 6);
  if (n >= NTOT) return;
  int lane = t & 63;
  int s     = __builtin_amdgcn_readfirstlane(row_ptr[n]);
  int e_end = __builtin_amdgcn_readfirstlane(row_ptr[n + 1]);
  float a0 = 0.f, a1 = 0.f, a2 = 0.f, a3 = 0.f;
  int p = s;
  for (; p + 4 <= e_end; p += 4) {
    int c0 = ecols[p], c1 = ecols[p + 1], c2 = ecols[p + 2], c3 = ecols[p + 3];
    float w0 = evals[p], w1 = evals[p + 1], w2 = evals[p + 2], w3 = evals[p + 3];
    float m0 = emb[c0 * 64 + lane];
    float m1 = emb[c1 * 64 + lane];
    float m2 = emb[c2 * 64 + lane];
    float m3 = emb[c3 * 64 + lane];
    a0 = fmaf(w0, m0, a0);
    a1 = fmaf(w1, m1, a1);
    a2 = fmaf(w2, m2, a2);
    a3 = fmaf(w3, m3, a3);
  }
  for (; p < e_end; ++p) {
    int c = ecols[p];
    a0 = fmaf(evals[p], emb[c * 64 + lane], a0);
  }
  float acc = (a0 + a1) + (a2 + a3);
  emb_out[n * 64 + lane] = acc;
  acc_out[n * 64 + lane] += acc;
}

extern "C" void kernel_launch(void* const* d_in, const int* in_sizes, int n_in,
                              void* d_out, int out_size, void* d_ws, size_t ws_size,
                              hipStream_t stream) {
  const int*   rows = (const int*)d_in[0];
  const int*   cols = (const int*)d_in[1];
  const float* vals = (const float*)d_in[2];
  const float* ue   = (const float*)d_in[3];
  const float* ie   = (const float*)d_in[4];
  const float* Wq   = (const float*)d_in[5];
  const float* Wk   = (const float*)d_in[6];
  const float* Wv   = (const float*)d_in[7];
  float* out = (float*)d_out;

  char* p = (char*)d_ws;
  auto alloc = [&](size_t b) { char* r = p; p += (b + 255) & ~(size_t)255; return (void*)r; };
  int*   cnt     = (int*)alloc((size_t)NTOT * 4);
  int*   row_ptr = (int*)alloc((size_t)(NTOT + 1) * 4);
  int*   cursor  = (int*)alloc((size_t)NTOT * 4);
  int*   bsums   = (int*)alloc(128 * 4);
  int*   boffs   = (int*)alloc(128 * 4);
  int*   ecols   = (int*)alloc((size_t)NEDGE * 4);
  float* evals   = (float*)alloc((size_t)NEDGE * 4);
  float* Q    = (float*)alloc((size_t)NTOT * 64 * 4);
  float* KV   = (float*)alloc((size_t)NTOT * 128 * 4);
  float* embA = (float*)alloc((size_t)NTOT * 64 * 4);
  float* embB = (float*)alloc((size_t)NTOT * 64 * 4);

  hipMemsetAsync(cnt, 0, (size_t)NTOT * 4, stream);
  k_hist<<<(NEDGE + 255) / 256, 256, 0, stream>>>(rows, cnt);
  int nblk = (NTOT + 2047) / 2048;  // 74
  k_scan1<<<nblk, 256, 0, stream>>>(cnt, row_ptr, bsums);
  k_scan2<<<1, 128, 0, stream>>>(bsums, boffs, nblk);
  k_scan3<<<(NTOT + 255) / 256, 256, 0, stream>>>(row_ptr, boffs, cursor);
  k_fill<<<(NEDGE + 255) / 256, 256, 0, stream>>>(rows, cols, vals, cursor, ecols, evals);
  k_init<<<(NTOT * 16 + 255) / 256, 256, 0, stream>>>(ue, ie, embA, out);

  float* cur = embA;
  float* nxt = embB;
  for (int l = 0; l < 2; ++l) {
    k_qkv<<<(NTOT / 8 + 3) / 4, 256, 0, stream>>>(cur, Wq + l * 4096, Wk + l * 4096, Wv + l * 4096,
                                                  Q, KV);
    k_gt<<<(NTOT + 3) / 4, 256, 0, stream>>>(Q, KV, row_ptr, ecols, nxt, out);
    float* tmp = cur; cur = nxt; nxt = tmp;
  }
  for (int l = 0; l < 2; ++l) {
    k_gcn<<<(NTOT + 3) / 4, 256, 0, stream>>>(cur, row_ptr, ecols, evals, nxt, out);
    float* tmp = cur; cur = nxt; nxt = tmp;
  }
}

// Round 3
// 643.125 us; speedup vs baseline: 1.5243x; 1.1964x over previous
//
#include <hip/hip_runtime.h>

#define NUSERS 100000
#define NITEMS 50000
#define NTOT   150000
#define NEDGE  1000000

// ---- init: emb = concat(user, item); out = emb (embeds_lst[0]) ----
__global__ void k_init(const float* __restrict__ ue, const float* __restrict__ ie,
                       float* __restrict__ emb, float* __restrict__ out) {
  int i = blockIdx.x * 256 + threadIdx.x;  // float4 index
  if (i >= NTOT * 16) return;
  float4 v = (i < NUSERS * 16) ? ((const float4*)ue)[i]
                               : ((const float4*)ie)[i - NUSERS * 16];
  ((float4*)emb)[i] = v;
  ((float4*)out)[i] = v;
}

// ---- CSR build: histogram -> scan -> fill ----
__global__ void k_hist(const int* __restrict__ rows, int* __restrict__ cnt) {
  int e = blockIdx.x * 256 + threadIdx.x;
  if (e < NEDGE) atomicAdd(&cnt[rows[e]], 1);
}

__global__ void k_scan1(const int* __restrict__ cnt, int* __restrict__ partial,
                        int* __restrict__ blocksums) {
  __shared__ int s[256];
  int t = threadIdx.x, b = blockIdx.x;
  int base = b * 2048 + t * 8;
  int pre[8]; int sum = 0;
  #pragma unroll
  for (int j = 0; j < 8; ++j) {
    int idx = base + j;
    int x = (idx < NTOT) ? cnt[idx] : 0;
    pre[j] = sum; sum += x;
  }
  s[t] = sum; __syncthreads();
  for (int off = 1; off < 256; off <<= 1) {
    int x = (t >= off) ? s[t - off] : 0;
    __syncthreads(); s[t] += x; __syncthreads();
  }
  int excl = s[t] - sum;
  #pragma unroll
  for (int j = 0; j < 8; ++j) {
    int idx = base + j;
    if (idx < NTOT) partial[idx] = excl + pre[j];
  }
  if (t == 255) blocksums[b] = s[255];
}

__global__ void k_scan2(const int* __restrict__ blocksums, int* __restrict__ blockoffs, int nblk) {
  __shared__ int s[128];
  int t = threadIdx.x;
  int x = (t < nblk) ? blocksums[t] : 0;
  s[t] = x; __syncthreads();
  for (int off = 1; off < 128; off <<= 1) {
    int y = (t >= off) ? s[t - off] : 0;
    __syncthreads(); s[t] += y; __syncthreads();
  }
  if (t < nblk) blockoffs[t] = s[t] - x;
}

__global__ void k_scan3(int* __restrict__ row_ptr, const int* __restrict__ blockoffs,
                        int* __restrict__ cursor) {
  int i = blockIdx.x * 256 + threadIdx.x;
  if (i < NTOT) {
    int v = row_ptr[i] + blockoffs[i >> 11];
    row_ptr[i] = v; cursor[i] = v;
  }
  if (i == 0) row_ptr[NTOT] = NEDGE;
}

__global__ void k_fill(const int* __restrict__ rows, const int* __restrict__ cols,
                       const float* __restrict__ vals, int* __restrict__ cursor,
                       int* __restrict__ ecols, float* __restrict__ evals) {
  int e = blockIdx.x * 256 + threadIdx.x;
  if (e >= NEDGE) return;
  int r = rows[e];
  int pos = atomicAdd(&cursor[r], 1);
  ecols[pos] = cols[e];
  evals[pos] = vals[e];
}

// ---- QKV projection v2: shuffle-free, LDS-staged emb tile ----
// Block = 256 threads = 4 waves; block handles 64 nodes (16 per wave).
// lane = output dim. Weights in natural [k][lane] layout (2-way bank = free).
// emb tile staged with stride 68 (16B-aligned float4 broadcasts).
#define ESTRIDE 68
__global__ void __launch_bounds__(256) k_qkv(const float* __restrict__ emb,
    const float* __restrict__ Wq, const float* __restrict__ Wk, const float* __restrict__ Wv,
    float* __restrict__ Q, float* __restrict__ KV) {
  __shared__ float wq[4096], wk[4096], wv[4096];
  __shared__ float es[64 * ESTRIDE];
  int t = threadIdx.x;
  for (int i = t; i < 4096; i += 256) { wq[i] = Wq[i]; wk[i] = Wk[i]; wv[i] = Wv[i]; }
  int n0 = blockIdx.x * 64;
  {
    int i = t >> 4, c = t & 15;  // node-row, float4 chunk
    #pragma unroll
    for (int r = 0; r < 4; ++r) {
      int li = i + r * 16;
      int node = n0 + li;
      float4 v = make_float4(0.f, 0.f, 0.f, 0.f);
      if (node < NTOT) v = ((const float4*)emb)[node * 16 + c];
      *(float4*)&es[li * ESTRIDE + c * 4] = v;
    }
  }
  __syncthreads();
  int wave = t >> 6, lane = t & 63;
  float qa[16], ka[16], va[16];
  #pragma unroll
  for (int u = 0; u < 16; ++u) { qa[u] = 0.f; ka[u] = 0.f; va[u] = 0.f; }
  const float* eb = &es[(wave * 16) * ESTRIDE];
  for (int k0 = 0; k0 < 64; k0 += 4) {
    float q0 = wq[(k0 + 0) * 64 + lane], q1 = wq[(k0 + 1) * 64 + lane];
    float q2 = wq[(k0 + 2) * 64 + lane], q3 = wq[(k0 + 3) * 64 + lane];
    float k0w = wk[(k0 + 0) * 64 + lane], k1w = wk[(k0 + 1) * 64 + lane];
    float k2w = wk[(k0 + 2) * 64 + lane], k3w = wk[(k0 + 3) * 64 + lane];
    float v0 = wv[(k0 + 0) * 64 + lane], v1 = wv[(k0 + 1) * 64 + lane];
    float v2 = wv[(k0 + 2) * 64 + lane], v3 = wv[(k0 + 3) * 64 + lane];
    #pragma unroll
    for (int u = 0; u < 16; ++u) {
      float4 e4 = *(const float4*)&eb[u * ESTRIDE + k0];  // broadcast
      qa[u] = fmaf(e4.x, q0, qa[u]);
      qa[u] = fmaf(e4.y, q1, qa[u]);
      qa[u] = fmaf(e4.z, q2, qa[u]);
      qa[u] = fmaf(e4.w, q3, qa[u]);
      ka[u] = fmaf(e4.x, k0w, ka[u]);
      ka[u] = fmaf(e4.y, k1w, ka[u]);
      ka[u] = fmaf(e4.z, k2w, ka[u]);
      ka[u] = fmaf(e4.w, k3w, ka[u]);
      va[u] = fmaf(e4.x, v0, va[u]);
      va[u] = fmaf(e4.y, v1, va[u]);
      va[u] = fmaf(e4.z, v2, va[u]);
      va[u] = fmaf(e4.w, v3, va[u]);
    }
  }
  #pragma unroll
  for (int u = 0; u < 16; ++u) {
    int n = n0 + wave * 16 + u;
    if (n < NTOT) {
      Q[n * 64 + lane] = qa[u];
      KV[n * 128 + lane] = ka[u];
      KV[n * 128 + 64 + lane] = va[u];
    }
  }
}

__device__ __forceinline__ float head_sum16(float x) {
  x += __shfl_xor(x, 1);
  x += __shfl_xor(x, 2);
  x += __shfl_xor(x, 4);
  x += __shfl_xor(x, 8);
  return x;
}

// ---- GT layer: one wave per destination node, 4x unrolled edge loop ----
__global__ void __launch_bounds__(256) k_gt(const float* __restrict__ Q,
    const float* __restrict__ KV, const int* __restrict__ row_ptr,
    const int* __restrict__ ecols, float* __restrict__ emb_out, float* __restrict__ acc_out) {
  int t = threadIdx.x;
  int n = blockIdx.x * 4 + (t >> 6);
  if (n >= NTOT) return;
  int lane = t & 63;
  float q = Q[n * 64 + lane];
  int s     = __builtin_amdgcn_readfirstlane(row_ptr[n]);
  int e_end = __builtin_amdgcn_readfirstlane(row_ptr[n + 1]);
  float den0 = 0.f, den1 = 0.f, acc0 = 0.f, acc1 = 0.f;
  int p = s;
  for (; p + 4 <= e_end; p += 4) {
    int c0 = ecols[p], c1 = ecols[p + 1], c2 = ecols[p + 2], c3 = ecols[p + 3];
    const float* b0 = KV + c0 * 128;
    const float* b1 = KV + c1 * 128;
    const float* b2 = KV + c2 * 128;
    const float* b3 = KV + c3 * 128;
    float k0 = b0[lane], k1 = b1[lane], k2 = b2[lane], k3 = b3[lane];
    float v0 = b0[64 + lane], v1 = b1[64 + lane], v2 = b2[64 + lane], v3 = b3[64 + lane];
    float x0 = head_sum16(q * k0);
    float x1 = head_sum16(q * k1);
    float x2 = head_sum16(q * k2);
    float x3 = head_sum16(q * k3);
    float e0 = __expf(fminf(fmaxf(x0, -10.f), 10.f));
    float e1 = __expf(fminf(fmaxf(x1, -10.f), 10.f));
    float e2 = __expf(fminf(fmaxf(x2, -10.f), 10.f));
    float e3 = __expf(fminf(fmaxf(x3, -10.f), 10.f));
    den0 += e0; den1 += e1; den0 += e2; den1 += e3;
    acc0 = fmaf(e0, v0, acc0); acc1 = fmaf(e1, v1, acc1);
    acc0 = fmaf(e2, v2, acc0); acc1 = fmaf(e3, v3, acc1);
  }
  for (; p < e_end; ++p) {
    int c = ecols[p];
    const float* b = KV + c * 128;
    float kv = b[lane], vv = b[64 + lane];
    float x = head_sum16(q * kv);
    float ex = __expf(fminf(fmaxf(x, -10.f), 10.f));
    den0 += ex;
    acc0 = fmaf(ex, vv, acc0);
  }
  float r = (acc0 + acc1) / ((den0 + den1) + 1e-8f);
  emb_out[n * 64 + lane] = r;
  acc_out[n * 64 + lane] += r;
}

// ---- GCN layer (spmm): one wave per destination node, 4x unrolled ----
__global__ void __launch_bounds__(256) k_gcn(const float* __restrict__ emb,
    const int* __restrict__ row_ptr, const int* __restrict__ ecols, const float* __restrict__ evals,
    float* __restrict__ emb_out, float* __restrict__ acc_out) {
  int t = threadIdx.x;
  int n = blockIdx.x * 4 + (t >> 6);
  if (n >= NTOT) return;
  int lane = t & 63;
  int s     = __builtin_amdgcn_readfirstlane(row_ptr[n]);
  int e_end = __builtin_amdgcn_readfirstlane(row_ptr[n + 1]);
  float a0 = 0.f, a1 = 0.f, a2 = 0.f, a3 = 0.f;
  int p = s;
  for (; p + 4 <= e_end; p += 4) {
    int c0 = ecols[p], c1 = ecols[p + 1], c2 = ecols[p + 2], c3 = ecols[p + 3];
    float w0 = evals[p], w1 = evals[p + 1], w2 = evals[p + 2], w3 = evals[p + 3];
    float m0 = emb[c0 * 64 + lane];
    float m1 = emb[c1 * 64 + lane];
    float m2 = emb[c2 * 64 + lane];
    float m3 = emb[c3 * 64 + lane];
    a0 = fmaf(w0, m0, a0);
    a1 = fmaf(w1, m1, a1);
    a2 = fmaf(w2, m2, a2);
    a3 = fmaf(w3, m3, a3);
  }
  for (; p < e_end; ++p) {
    int c = ecols[p];
    a0 = fmaf(evals[p], emb[c * 64 + lane], a0);
  }
  float acc = (a0 + a1) + (a2 + a3);
  emb_out[n * 64 + lane] = acc;
  acc_out[n * 64 + lane] += acc;
}

extern "C" void kernel_launch(void* const* d_in, const int* in_sizes, int n_in,
                              void* d_out, int out_size, void* d_ws, size_t ws_size,
                              hipStream_t stream) {
  const int*   rows = (const int*)d_in[0];
  const int*   cols = (const int*)d_in[1];
  const float* vals = (const float*)d_in[2];
  const float* ue   = (const float*)d_in[3];
  const float* ie   = (const float*)d_in[4];
  const float* Wq   = (const float*)d_in[5];
  const float* Wk   = (const float*)d_in[6];
  const float* Wv   = (const float*)d_in[7];
  float* out = (float*)d_out;

  char* p = (char*)d_ws;
  auto alloc = [&](size_t b) { char* r = p; p += (b + 255) & ~(size_t)255; return (void*)r; };
  int*   cnt     = (int*)alloc((size_t)NTOT * 4);
  int*   row_ptr = (int*)alloc((size_t)(NTOT + 1) * 4);
  int*   cursor  = (int*)alloc((size_t)NTOT * 4);
  int*   bsums   = (int*)alloc(128 * 4);
  int*   boffs   = (int*)alloc(128 * 4);
  int*   ecols   = (int*)alloc((size_t)NEDGE * 4);
  float* evals   = (float*)alloc((size_t)NEDGE * 4);
  float* Q    = (float*)alloc((size_t)NTOT * 64 * 4);
  float* KV   = (float*)alloc((size_t)NTOT * 128 * 4);
  float* embA = (float*)alloc((size_t)NTOT * 64 * 4);
  float* embB = (float*)alloc((size_t)NTOT * 64 * 4);

  hipMemsetAsync(cnt, 0, (size_t)NTOT * 4, stream);
  k_hist<<<(NEDGE + 255) / 256, 256, 0, stream>>>(rows, cnt);
  int nblk = (NTOT + 2047) / 2048;  // 74
  k_scan1<<<nblk, 256, 0, stream>>>(cnt, row_ptr, bsums);
  k_scan2<<<1, 128, 0, stream>>>(bsums, boffs, nblk);
  k_scan3<<<(NTOT + 255) / 256, 256, 0, stream>>>(row_ptr, boffs, cursor);
  k_fill<<<(NEDGE + 255) / 256, 256, 0, stream>>>(rows, cols, vals, cursor, ecols, evals);
  k_init<<<(NTOT * 16 + 255) / 256, 256, 0, stream>>>(ue, ie, embA, out);

  float* cur = embA;
  float* nxt = embB;
  for (int l = 0; l < 2; ++l) {
    k_qkv<<<(NTOT + 63) / 64, 256, 0, stream>>>(cur, Wq + l * 4096, Wk + l * 4096, Wv + l * 4096,
                                                Q, KV);
    k_gt<<<(NTOT + 3) / 4, 256, 0, stream>>>(Q, KV, row_ptr, ecols, nxt, out);
    float* tmp = cur; cur = nxt; nxt = tmp;
  }
  for (int l = 0; l < 2; ++l) {
    k_gcn<<<(NTOT + 3) / 4, 256, 0, stream>>>(cur, row_ptr, ecols, evals, nxt, out);
    float* tmp = cur; cur = nxt; nxt = tmp;
  }
}